// Round 5
// baseline (314.129 us; speedup 1.0000x reference)
//
#include <hip/hip_runtime.h>
#include <math.h>

#define NB 256
#define NS 2048
#define ND 128
#define NU 64
#define NT 512
#define SH 1024          // rows per block (S split in 2)
#define TS 64            // tile rows
#define NTILE (SH / TS)  // 16
#define WR 8             // rows per wave per tile

typedef _Float16 f16x8 __attribute__((ext_vector_type(8)));
typedef float f32x4 __attribute__((ext_vector_type(4)));

#define GLDS16(gp, lp)                                                        \
  __builtin_amdgcn_global_load_lds(                                           \
      (const __attribute__((address_space(1))) void*)(gp),                    \
      (__attribute__((address_space(3))) void*)(lp), 16, 0, 0)

__device__ __forceinline__ float tanh_fast(float v) {
  // tanh(v) = 1 - 2/(exp(2v)+1); exact saturation for large |v|.
  const float e = __expf(2.0f * v);
  return 1.0f - 2.0f * __builtin_amdgcn_rcpf(e + 1.0f);
}

__global__ __launch_bounds__(NT, 4) void addattn_stream(
    const float* __restrict__ x,     // [NB][NS][ND]
    const float* __restrict__ W1,    // [ND][NU]
    const float* __restrict__ W2,    // [NU]
    const float* __restrict__ bias,  // [NU]
    float* __restrict__ out,         // ctx [NB][ND] ++ alpha [NB][NS]
    float* __restrict__ ws)          // [256 cnt(int)][512 l][512*128 ctx part]
{
  // Per-wave private slices: wave wv owns tile rows [wv*8, wv*8+8), stages
  // them itself, waits only on its own vmcnt. No barrier in the main loop.
  // Swizzle: slice float4 slot (s, c) holds source column c ^ s.
  __shared__ __align__(16) float xbuf[2][TS * ND];  // 2 x 32 KiB
  __shared__ __align__(16) float part[16][ND];      // 8 KiB ctx partials
  __shared__ float red[8];
  __shared__ int flag;

  const int bid = blockIdx.x;
  const int b = bid >> 1;
  const int h = bid & 1;
  const int t = threadIdx.x;
  const int lane = t & 63;
  const int wv = t >> 6;     // wave 0..7
  const int l15 = lane & 15;
  const int hi = lane >> 4;  // 0..3
  const float* xb = x + (size_t)b * NS * ND + (size_t)h * SH * ND;
  float* aexp = out + NB * ND + (size_t)b * NS + h * SH;  // exp(score) staging

  // ---- per-wave tile staging: 4 x (64 lanes x 16B) = wave's 8 rows (4 KiB)
  auto stage = [&](int bi, int ti) {
    const float* src = xb + (size_t)ti * TS * ND + wv * WR * ND;
    float* dst = &xbuf[bi][wv * WR * ND];
#pragma unroll
    for (int j = 0; j < 4; ++j) {
      const int L = j * 64 + lane;   // 16B slot in the 256-slot slice
      const int s = L >> 5;          // slice row 0..7
      const int d4 = (L & 31) ^ s;   // source float4 column (s&7 == s)
      GLDS16(src + s * ND + d4 * 4, dst + L * 4);
    }
  };

  stage(0, 0);  // HBM starts immediately; W1 latency hides under it

  // ---- A fragments: W1^T [64u x 128k], kept in registers for the kernel.
  //      afrag[mt][kt]: A[m = mt*16 + (lane&15)][k = kt*32 + (lane>>4)*8 + j]
  f16x8 afrag[4][4];
#pragma unroll
  for (int mt = 0; mt < 4; ++mt) {
#pragma unroll
    for (int kt = 0; kt < 4; ++kt) {
      const int u = mt * 16 + l15;
      const int k0 = kt * 32 + hi * 8;
      f16x8 a;
#pragma unroll
      for (int j = 0; j < 8; ++j) a[j] = (_Float16)W1[(k0 + j) * NU + u];
      afrag[mt][kt] = a;
    }
  }
  // bias/W2 for this lane's C-fragment rows: u = mt*16 + (lane>>4)*4 + r
  float breg[4][4], wreg[4][4];
#pragma unroll
  for (int mt = 0; mt < 4; ++mt) {
#pragma unroll
    for (int r = 0; r < 4; ++r) {
      const int u = mt * 16 + hi * 4 + r;
      breg[mt][r] = bias[u];
      wreg[mt][r] = W2[u];
    }
  }

  stage(1, 1);  // second buffer in flight

  f32x4 ctxa = {0.f, 0.f, 0.f, 0.f};  // running exp(s)*x partial
  float lsum = 0.f;
  const int dq = lane & 31;           // ctx float4 column
  const int rloc = (lane >> 5) * 4;   // ctx local rows rloc..rloc+3
  const int r = l15 & 7;              // this lane's B row (cols 8-15 duplicate)

  for (int ti = 0; ti < NTILE; ++ti) {
    const int cur = ti & 1;
    // Per-wave counted wait: tile ti resident, tile ti+1 still in flight.
    if (ti < NTILE - 1) {
      asm volatile("s_waitcnt vmcnt(4)" ::: "memory");
    } else {
      asm volatile("s_waitcnt vmcnt(0)" ::: "memory");
    }
    __builtin_amdgcn_sched_barrier(0);
    const float* xs = &xbuf[cur][wv * WR * ND];  // this wave's slice

    // ---- scores: P^T = W1^T (A) x^T (B); wave's 8 rows as B cols (x2 dup)
    f32x4 acc[4];
#pragma unroll
    for (int mt = 0; mt < 4; ++mt) acc[mt] = (f32x4){0.f, 0.f, 0.f, 0.f};
    const int rb = r * 32;
#pragma unroll
    for (int kt = 0; kt < 4; ++kt) {
      const int d4a = kt * 8 + hi * 2;
      const float4 v0 = *(const float4*)(xs + (rb + ((d4a + 0) ^ r)) * 4);
      const float4 v1 = *(const float4*)(xs + (rb + ((d4a + 1) ^ r)) * 4);
      f16x8 bf;
      bf[0] = (_Float16)v0.x; bf[1] = (_Float16)v0.y;
      bf[2] = (_Float16)v0.z; bf[3] = (_Float16)v0.w;
      bf[4] = (_Float16)v1.x; bf[5] = (_Float16)v1.y;
      bf[6] = (_Float16)v1.z; bf[7] = (_Float16)v1.w;
#pragma unroll
      for (int mt = 0; mt < 4; ++mt)
        acc[mt] = __builtin_amdgcn_mfma_f32_16x16x32_f16(afrag[mt][kt], bf,
                                                         acc[mt], 0, 0, 0);
    }
    // ---- epilogue: score2 = sum_u tanh(P + b)*W2; reduce over lane-hi
    float s2 = 0.f;
#pragma unroll
    for (int mt = 0; mt < 4; ++mt) {
#pragma unroll
      for (int rr = 0; rr < 4; ++rr)
        s2 = fmaf(tanh_fast(acc[mt][rr] + breg[mt][rr]), wreg[mt][rr], s2);
    }
    s2 += __shfl_xor(s2, 16);
    s2 += __shfl_xor(s2, 32);
    // |score2| <= sum|W2| ~ 6.4 -> exp() safe in fp32, no max subtraction.
    const float p = __expf(s2);  // lane L holds p for local row (L&7)
    if (lane < 8) {
      aexp[ti * TS + wv * WR + lane] = p;  // stage exp into alpha region
      lsum += p;
    }

    // ---- ctx accumulation over this wave's 8 rows (p via shfl)
#pragma unroll
    for (int r4 = 0; r4 < 4; ++r4) {
      const int sr = rloc + r4;  // local row 0..7
      const float pv = __shfl(p, sr);
      const float4 xv = *(const float4*)(xs + (sr * 32 + (dq ^ sr)) * 4);
      ctxa[0] = fmaf(pv, xv.x, ctxa[0]);
      ctxa[1] = fmaf(pv, xv.y, ctxa[1]);
      ctxa[2] = fmaf(pv, xv.z, ctxa[2]);
      ctxa[3] = fmaf(pv, xv.w, ctxa[3]);
    }

    // Re-stage this wave's slice for tile ti+2 (only this wave touches it).
    if (ti + 2 < NTILE) stage(cur, ti + 2);
  }

  // ---- block finale: partial l and partial ctx -> workspace
  *(float4*)(&part[wv * 2 + (lane >> 5)][dq * 4]) =
      make_float4(ctxa[0], ctxa[1], ctxa[2], ctxa[3]);
  lsum += __shfl_xor(lsum, 1);
  lsum += __shfl_xor(lsum, 2);
  lsum += __shfl_xor(lsum, 4);  // lane0 = sum over this wave's 8 rows/tile
  if (lane == 0) red[wv] = lsum;
  __syncthreads();

  int* cnt = (int*)ws;            // [256], zeroed by memset each launch
  float* wl = ws + 256;           // [512] partial l
  float* wc = ws + 256 + 512;     // [512][128] partial ctx
  if (t < ND) {
    float c = 0.f;
#pragma unroll
    for (int g = 0; g < 16; ++g) c += part[g][t];
    wc[(size_t)bid * ND + t] = c;
  }
  if (t == 0) {
    float l = 0.f;
#pragma unroll
    for (int j = 0; j < 8; ++j) l += red[j];
    wl[bid] = l;
  }
  // release: make this block's ws + aexp writes device-visible
  __threadfence();
  __syncthreads();
  if (t == 0) flag = (atomicAdd(&cnt[b], 1) == 1) ? 1 : 0;
  __syncthreads();

  // ---- last arriver of the pair combines (non-blocking, order-free)
  if (flag) {
    __threadfence();  // acquire: see the other block's writes
    const float ltot = wl[b * 2] + wl[b * 2 + 1];
    const float inv = 1.0f / ltot;
    float* al = out + NB * ND + (size_t)b * NS;
#pragma unroll
    for (int j = 0; j < 4; ++j) al[t + j * NT] *= inv;  // exp -> alpha
    if (t < ND)
      out[(size_t)b * ND + t] =
          (wc[(size_t)(b * 2) * ND + t] + wc[(size_t)(b * 2 + 1) * ND + t]) *
          inv;
  }
}

extern "C" void kernel_launch(void* const* d_in, const int* in_sizes, int n_in,
                              void* d_out, int out_size, void* d_ws,
                              size_t ws_size, hipStream_t stream) {
  const float* x = (const float*)d_in[0];
  const float* W1 = (const float*)d_in[1];
  const float* W2 = (const float*)d_in[2];
  const float* bias = (const float*)d_in[3];
  float* out = (float*)d_out;
  float* ws = (float*)d_ws;
  // zero the per-batch arrival counters (harness does not re-poison ws)
  hipMemsetAsync(d_ws, 0, NB * sizeof(int), stream);
  addattn_stream<<<NB * 2, NT, 0, stream>>>(x, W1, W2, bias, out, ws);
}

// Round 6
// 231.431 us; speedup vs baseline: 1.3573x; 1.3573x over previous
//
#include <hip/hip_runtime.h>
#include <math.h>

#define NB 256
#define NS 2048
#define ND 128
#define NU 64
#define NT 512
#define SH 1024          // rows per block (S split in 2)
#define TS 64            // tile rows
#define NTILE (SH / TS)  // 16
#define WR 8             // rows per wave per tile

typedef _Float16 f16x8 __attribute__((ext_vector_type(8)));
typedef float f32x4 __attribute__((ext_vector_type(4)));

#define GLDS16(gp, lp)                                                        \
  __builtin_amdgcn_global_load_lds(                                           \
      (const __attribute__((address_space(1))) void*)(gp),                    \
      (__attribute__((address_space(3))) void*)(lp), 16, 0, 0)

__device__ __forceinline__ float tanh_fast(float v) {
  // tanh(v) = 1 - 2/(exp(2v)+1); exact saturation for large |v|.
  const float e = __expf(2.0f * v);
  return 1.0f - 2.0f * __builtin_amdgcn_rcpf(e + 1.0f);
}

__global__ __launch_bounds__(NT, 4) void addattn_stream(
    const float* __restrict__ x,     // [NB][NS][ND]
    const float* __restrict__ W1,    // [ND][NU]
    const float* __restrict__ W2,    // [NU]
    const float* __restrict__ bias,  // [NU]
    float* __restrict__ out,         // ctx [NB][ND] ++ alpha [NB][NS]
    float* __restrict__ ws)          // [256 cnt(int)][512 l][512*128 ctx part]
{
  // LDS = 2*32KiB xbuf + 16KiB W1 fragments = exactly 81920 B -> 2 blocks/CU.
  // W1 A-fragments live in SHARED LDS (not per-wave registers): this is what
  // keeps VGPR <= 128 at 4 waves/EU (round-5 spilled them to scratch).
  __shared__ __align__(16) float xbuf[2][TS * ND];       // 2 x 32 KiB
  __shared__ __align__(16) _Float16 w1f[16 * 64 * 8];    // 16 KiB: [frag][lane][8]

  const int bid = blockIdx.x;
  const int b = bid >> 1;
  const int h = bid & 1;
  const int t = threadIdx.x;
  const int lane = t & 63;
  const int wv = t >> 6;     // wave 0..7
  const int l15 = lane & 15;
  const int hi = lane >> 4;  // 0..3
  const float* xb = x + (size_t)b * NS * ND + (size_t)h * SH * ND;
  float* aexp = out + NB * ND + (size_t)b * NS + h * SH;  // exp(score) staging

  // ---- per-wave tile staging: 4 x (64 lanes x 16B) = wave's 8 rows (4 KiB).
  // Swizzle: slice float4 slot (s, c) holds source column c ^ s.
  auto stage = [&](int bi, int ti) {
    const float* src = xb + (size_t)ti * TS * ND + wv * WR * ND;
    float* dst = &xbuf[bi][wv * WR * ND];
#pragma unroll
    for (int j = 0; j < 4; ++j) {
      const int L = j * 64 + lane;   // 16B slot in the 256-slot slice
      const int s = L >> 5;          // slice row 0..7
      const int d4 = (L & 31) ^ s;   // source float4 column
      GLDS16(src + s * ND + d4 * 4, dst + L * 4);
    }
  };

  stage(0, 0);  // HBM starts immediately

  // ---- build W1^T fragments in LDS: frag f=(mt*4+kt), lane ln holds
  //      A[m=mt*16+(ln&15)][k=kt*32+(ln>>4)*8+j] as f16x8.
#pragma unroll
  for (int S = 0; S < 1024; S += NT) {
    const int s = S + t;
    const int f = s >> 6, ln = s & 63;
    const int mt = f >> 2, kt = f & 3;
    const int u = mt * 16 + (ln & 15);
    const int k0 = kt * 32 + (ln >> 4) * 8;
    f16x8 a;
#pragma unroll
    for (int j = 0; j < 8; ++j) a[j] = (_Float16)W1[(k0 + j) * NU + u];
    *(f16x8*)&w1f[s * 8] = a;
  }
  // bias/W2 for this lane's C-fragment rows: u = mt*16 + (lane>>4)*4 + r
  float breg[4][4], wreg[4][4];
#pragma unroll
  for (int mt = 0; mt < 4; ++mt) {
#pragma unroll
    for (int r = 0; r < 4; ++r) {
      const int u = mt * 16 + hi * 4 + r;
      breg[mt][r] = bias[u];
      wreg[mt][r] = W2[u];
    }
  }

  stage(1, 1);     // second buffer in flight
  __syncthreads(); // w1f visible to all waves (one-time prologue barrier)

  f32x4 ctxa = {0.f, 0.f, 0.f, 0.f};  // running exp(s)*x partial
  float lsum = 0.f;
  const int dq = lane & 31;            // ctx float4 column
  const int rloc = (lane >> 5) * 4;    // ctx local rows rloc..rloc+3
  const int r = l15 & 7;               // this lane's B row (cols 8-15 dup)

  for (int ti = 0; ti < NTILE; ++ti) {
    const int cur = ti & 1;
    // Per-wave counted wait: tile ti resident, tile ti+1 still in flight.
    if (ti < NTILE - 1) {
      asm volatile("s_waitcnt vmcnt(4)" ::: "memory");
    } else {
      asm volatile("s_waitcnt vmcnt(0)" ::: "memory");
    }
    __builtin_amdgcn_sched_barrier(0);
    const float* xs = &xbuf[cur][wv * WR * ND];  // this wave's slice

    // ---- scores: P^T = W1^T (A, from LDS) x^T (B); 8 rows as B cols (x2)
    f32x4 acc[4];
#pragma unroll
    for (int mt = 0; mt < 4; ++mt) acc[mt] = (f32x4){0.f, 0.f, 0.f, 0.f};
    const int rb = r * 32;
#pragma unroll
    for (int kt = 0; kt < 4; ++kt) {
      const int d4a = kt * 8 + hi * 2;
      const float4 v0 = *(const float4*)(xs + (rb + ((d4a + 0) ^ r)) * 4);
      const float4 v1 = *(const float4*)(xs + (rb + ((d4a + 1) ^ r)) * 4);
      f16x8 bf;
      bf[0] = (_Float16)v0.x; bf[1] = (_Float16)v0.y;
      bf[2] = (_Float16)v0.z; bf[3] = (_Float16)v0.w;
      bf[4] = (_Float16)v1.x; bf[5] = (_Float16)v1.y;
      bf[6] = (_Float16)v1.z; bf[7] = (_Float16)v1.w;
#pragma unroll
      for (int mt = 0; mt < 4; ++mt) {
        const f16x8 af = *(const f16x8*)&w1f[((mt * 4 + kt) * 64 + lane) * 8];
        acc[mt] = __builtin_amdgcn_mfma_f32_16x16x32_f16(af, bf, acc[mt],
                                                         0, 0, 0);
      }
    }
    // ---- epilogue: score2 = sum_u tanh(P + b)*W2; reduce over lane-hi
    float s2 = 0.f;
#pragma unroll
    for (int mt = 0; mt < 4; ++mt) {
#pragma unroll
      for (int rr = 0; rr < 4; ++rr)
        s2 = fmaf(tanh_fast(acc[mt][rr] + breg[mt][rr]), wreg[mt][rr], s2);
    }
    s2 += __shfl_xor(s2, 16);
    s2 += __shfl_xor(s2, 32);
    // |score2| <= sum|W2| ~ 6.4 -> exp() safe in fp32, no max subtraction.
    const float p = __expf(s2);  // lane L holds p for local row (L&7)
    if (lane < 8) {
      aexp[ti * TS + wv * WR + lane] = p;  // stage exp into alpha region
      lsum += p;
    }

    // ---- ctx accumulation over this wave's 8 rows (p via shfl)
#pragma unroll
    for (int r4 = 0; r4 < 4; ++r4) {
      const int sr = rloc + r4;  // local row 0..7
      const float pv = __shfl(p, sr);
      const float4 xv = *(const float4*)(xs + (sr * 32 + (dq ^ sr)) * 4);
      ctxa[0] = fmaf(pv, xv.x, ctxa[0]);
      ctxa[1] = fmaf(pv, xv.y, ctxa[1]);
      ctxa[2] = fmaf(pv, xv.z, ctxa[2]);
      ctxa[3] = fmaf(pv, xv.w, ctxa[3]);
    }

    // Re-stage this wave's slice for tile ti+2 (only this wave touches it).
    if (ti + 2 < NTILE) stage(cur, ti + 2);
  }

  // ---- block finale. Scratch lives in THIS WAVE'S OWN xbuf[0] slice (only
  // this wave might still be reading it), so no cross-wave hazard before the
  // barrier. Layout per wave slice: [0..255] two ctx partial rows, [256] l.
  float* myslice = &xbuf[0][wv * WR * ND];
  *(float4*)(myslice + (lane >> 5) * ND + dq * 4) =
      make_float4(ctxa[0], ctxa[1], ctxa[2], ctxa[3]);
  lsum += __shfl_xor(lsum, 1);
  lsum += __shfl_xor(lsum, 2);
  lsum += __shfl_xor(lsum, 4);  // lanes<8 now hold wave total
  if (lane == 0) myslice[2 * ND] = lsum;
  __syncthreads();

  int* cnt = (int*)ws;            // [256], zeroed by memset each launch
  float* wl = ws + 256;           // [512] partial l
  float* wc = ws + 256 + 512;     // [512][128] partial ctx
  if (t < ND) {
    float c = 0.f;
#pragma unroll
    for (int g = 0; g < 16; ++g)
      c += xbuf[0][(g >> 1) * WR * ND + (g & 1) * ND + t];
    wc[(size_t)bid * ND + t] = c;
  }
  if (t == 0) {
    float l = 0.f;
#pragma unroll
    for (int j = 0; j < 8; ++j) l += xbuf[0][j * WR * ND + 2 * ND];
    wl[bid] = l;
  }
  // release: make this block's ws + aexp writes device-visible
  __threadfence();
  __syncthreads();
  int* flag = (int*)&xbuf[1][0];  // xbuf free after the barrier
  if (t == 0) *flag = (atomicAdd(&cnt[b], 1) == 1) ? 1 : 0;
  __syncthreads();

  // ---- last arriver of the pair combines (non-blocking, order-free)
  if (*flag) {
    __threadfence();  // acquire: see the other block's writes
    const float ltot = wl[b * 2] + wl[b * 2 + 1];
    const float inv = 1.0f / ltot;
    float* al = out + NB * ND + (size_t)b * NS;
#pragma unroll
    for (int j = 0; j < 4; ++j) al[t + j * NT] *= inv;  // exp -> alpha
    if (t < ND)
      out[(size_t)b * ND + t] =
          (wc[(size_t)(b * 2) * ND + t] + wc[(size_t)(b * 2 + 1) * ND + t]) *
          inv;
  }
}

extern "C" void kernel_launch(void* const* d_in, const int* in_sizes, int n_in,
                              void* d_out, int out_size, void* d_ws,
                              size_t ws_size, hipStream_t stream) {
  const float* x = (const float*)d_in[0];
  const float* W1 = (const float*)d_in[1];
  const float* W2 = (const float*)d_in[2];
  const float* bias = (const float*)d_in[3];
  float* out = (float*)d_out;
  float* ws = (float*)d_ws;
  // zero the per-batch arrival counters (harness does not re-poison ws)
  hipMemsetAsync(d_ws, 0, NB * sizeof(int), stream);
  addattn_stream<<<NB * 2, NT, 0, stream>>>(x, W1, W2, bias, out, ws);
}

// Round 7
// 55.588 us; speedup vs baseline: 5.6510x; 4.1633x over previous
//
#include <hip/hip_runtime.h>
#include <math.h>

#define NB 256
#define NS 2048
#define ND 128
#define NU 64
#define NT 512
#define SH 1024          // rows per stream-block (S split in 2)
#define TS 64            // tile rows
#define NTILE (SH / TS)  // 16
#define WR 8             // rows per wave per tile

typedef _Float16 f16x8 __attribute__((ext_vector_type(8)));
typedef float f32x4 __attribute__((ext_vector_type(4)));

#define GLDS16(gp, lp)                                                        \
  __builtin_amdgcn_global_load_lds(                                           \
      (const __attribute__((address_space(1))) void*)(gp),                    \
      (__attribute__((address_space(3))) void*)(lp), 16, 0, 0)

__device__ __forceinline__ float tanh_fast(float v) {
  // tanh(v) = 1 - 2/(exp(2v)+1); exact saturation for large |v|.
  const float e = __expf(2.0f * v);
  return 1.0f - 2.0f * __builtin_amdgcn_rcpf(e + 1.0f);
}

// ---------------------------------------------------------------------------
// Kernel 1: stream x, compute exp(score) + per-block partial l and ctx.
// NO cross-block communication (no atomics, no fences) — visibility of the
// plain stores is provided by the kernel boundary before kernel 2.
// LDS = 2*32KiB xbuf + 16KiB W1 frags = 81920 B exactly -> 2 blocks/CU.
// ---------------------------------------------------------------------------
__global__ __launch_bounds__(NT, 4) void addattn_stream(
    const float* __restrict__ x,     // [NB][NS][ND]
    const float* __restrict__ W1,    // [ND][NU]
    const float* __restrict__ W2,    // [NU]
    const float* __restrict__ bias,  // [NU]
    float* __restrict__ out,         // ctx [NB][ND] ++ alpha [NB][NS]
    float* __restrict__ ws)          // [512 l][512*128 ctx partials]
{
  __shared__ __align__(16) float xbuf[2][TS * ND];     // 2 x 32 KiB
  __shared__ __align__(16) _Float16 w1f[16 * 64 * 8];  // 16 KiB [frag][lane][8]

  const int bid = blockIdx.x;
  const int b = bid >> 1;
  const int h = bid & 1;
  const int t = threadIdx.x;
  const int lane = t & 63;
  const int wv = t >> 6;     // wave 0..7
  const int l15 = lane & 15;
  const int hi = lane >> 4;  // 0..3
  const float* xb = x + (size_t)b * NS * ND + (size_t)h * SH * ND;
  float* aexp = out + NB * ND + (size_t)b * NS + h * SH;  // exp(score) staging

  // ---- per-wave tile staging: 4 x (64 lanes x 16B) = wave's 8 rows (4 KiB).
  // Swizzle: slice float4 slot (s, c) holds source column c ^ s.
  auto stage = [&](int bi, int ti) {
    const float* src = xb + (size_t)ti * TS * ND + wv * WR * ND;
    float* dst = &xbuf[bi][wv * WR * ND];
#pragma unroll
    for (int j = 0; j < 4; ++j) {
      const int L = j * 64 + lane;  // 16B slot in the 256-slot slice
      const int s = L >> 5;         // slice row 0..7
      const int d4 = (L & 31) ^ s;  // source float4 column
      GLDS16(src + s * ND + d4 * 4, dst + L * 4);
    }
  };

  stage(0, 0);  // HBM starts immediately

  // ---- build W1^T fragments in LDS: frag f=(mt*4+kt), lane ln holds
  //      A[m=mt*16+(ln&15)][k=kt*32+(ln>>4)*8+j] as f16x8.
#pragma unroll
  for (int S = 0; S < 1024; S += NT) {
    const int s = S + t;
    const int f = s >> 6, ln = s & 63;
    const int mt = f >> 2, kt = f & 3;
    const int u = mt * 16 + (ln & 15);
    const int k0 = kt * 32 + (ln >> 4) * 8;
    f16x8 a;
#pragma unroll
    for (int j = 0; j < 8; ++j) a[j] = (_Float16)W1[(k0 + j) * NU + u];
    *(f16x8*)&w1f[s * 8] = a;
  }
  // bias/W2 for this lane's C-fragment rows: u = mt*16 + (lane>>4)*4 + r
  float breg[4][4], wreg[4][4];
#pragma unroll
  for (int mt = 0; mt < 4; ++mt) {
#pragma unroll
    for (int r = 0; r < 4; ++r) {
      const int u = mt * 16 + hi * 4 + r;
      breg[mt][r] = bias[u];
      wreg[mt][r] = W2[u];
    }
  }

  stage(1, 1);      // second buffer in flight
  __syncthreads();  // w1f visible (one-time prologue barrier)

  f32x4 ctxa = {0.f, 0.f, 0.f, 0.f};  // running exp(s)*x partial
  float lsum = 0.f;
  const int dq = lane & 31;          // ctx float4 column
  const int rloc = (lane >> 5) * 4;  // ctx local rows rloc..rloc+3
  const int r = l15 & 7;             // this lane's B row (cols 8-15 dup)

  for (int ti = 0; ti < NTILE; ++ti) {
    const int cur = ti & 1;
    // Counted wait: my 4 tile-ti loads are my oldest outstanding (FIFO);
    // vmcnt(5) lets the ti-1 aexp store + tile ti+1's 4 loads stay in flight.
    if (ti < NTILE - 1) {
      asm volatile("s_waitcnt vmcnt(5)" ::: "memory");
    } else {
      asm volatile("s_waitcnt vmcnt(0)" ::: "memory");
    }
    __builtin_amdgcn_sched_barrier(0);
    const float* xs = &xbuf[cur][wv * WR * ND];  // this wave's slice

    // ---- scores: P^T = W1^T (A, from LDS) x^T (B); 8 rows as B cols (x2)
    f32x4 acc[4];
#pragma unroll
    for (int mt = 0; mt < 4; ++mt) acc[mt] = (f32x4){0.f, 0.f, 0.f, 0.f};
    const int rb = r * 32;
#pragma unroll
    for (int kt = 0; kt < 4; ++kt) {
      const int d4a = kt * 8 + hi * 2;
      const float4 v0 = *(const float4*)(xs + (rb + ((d4a + 0) ^ r)) * 4);
      const float4 v1 = *(const float4*)(xs + (rb + ((d4a + 1) ^ r)) * 4);
      f16x8 bf;
      bf[0] = (_Float16)v0.x; bf[1] = (_Float16)v0.y;
      bf[2] = (_Float16)v0.z; bf[3] = (_Float16)v0.w;
      bf[4] = (_Float16)v1.x; bf[5] = (_Float16)v1.y;
      bf[6] = (_Float16)v1.z; bf[7] = (_Float16)v1.w;
#pragma unroll
      for (int mt = 0; mt < 4; ++mt) {
        const f16x8 af = *(const f16x8*)&w1f[((mt * 4 + kt) * 64 + lane) * 8];
        acc[mt] =
            __builtin_amdgcn_mfma_f32_16x16x32_f16(af, bf, acc[mt], 0, 0, 0);
      }
    }
    // ---- epilogue: score2 = sum_u tanh(P + b)*W2; reduce over lane-hi
    float s2 = 0.f;
#pragma unroll
    for (int mt = 0; mt < 4; ++mt) {
#pragma unroll
      for (int rr = 0; rr < 4; ++rr)
        s2 = fmaf(tanh_fast(acc[mt][rr] + breg[mt][rr]), wreg[mt][rr], s2);
    }
    s2 += __shfl_xor(s2, 16);
    s2 += __shfl_xor(s2, 32);
    // |score2| <= sum|W2| ~ 6.4 -> exp() safe in fp32, no max subtraction.
    const float p = __expf(s2);  // lane L holds p for local row (L&7)
    if (lane < 8) {
      aexp[ti * TS + wv * WR + lane] = p;  // plain store; kernel2 reads it
      lsum += p;
    }

    // ---- ctx accumulation over this wave's 8 rows (p via shfl)
#pragma unroll
    for (int r4 = 0; r4 < 4; ++r4) {
      const int sr = rloc + r4;  // local row 0..7
      const float pv = __shfl(p, sr);
      const float4 xv = *(const float4*)(xs + (sr * 32 + (dq ^ sr)) * 4);
      ctxa[0] = fmaf(pv, xv.x, ctxa[0]);
      ctxa[1] = fmaf(pv, xv.y, ctxa[1]);
      ctxa[2] = fmaf(pv, xv.z, ctxa[2]);
      ctxa[3] = fmaf(pv, xv.w, ctxa[3]);
    }

    // Re-stage this wave's slice for tile ti+2 (only this wave touches it).
    if (ti + 2 < NTILE) stage(cur, ti + 2);
  }

  // ---- block finale: partials into THIS WAVE'S OWN xbuf[0] slice (no
  // cross-wave hazard before the barrier), then one reduce + global write.
  float* myslice = &xbuf[0][wv * WR * ND];
  *(float4*)(myslice + (lane >> 5) * ND + dq * 4) =
      make_float4(ctxa[0], ctxa[1], ctxa[2], ctxa[3]);
  lsum += __shfl_xor(lsum, 1);
  lsum += __shfl_xor(lsum, 2);
  lsum += __shfl_xor(lsum, 4);  // lanes<8 hold wave total
  if (lane == 0) myslice[2 * ND] = lsum;
  __syncthreads();

  float* wl = ws;        // [512] partial l
  float* wc = ws + 512;  // [512][128] partial ctx
  if (t < ND) {
    float c = 0.f;
#pragma unroll
    for (int g = 0; g < 16; ++g)
      c += xbuf[0][(g >> 1) * WR * ND + (g & 1) * ND + t];
    wc[(size_t)bid * ND + t] = c;
  }
  if (t == 0) {
    float l = 0.f;
#pragma unroll
    for (int j = 0; j < 8; ++j) l += xbuf[0][j * WR * ND + 2 * ND];
    wl[bid] = l;
  }
}

// ---------------------------------------------------------------------------
// Kernel 2: per batch, combine the two half partials; normalize alpha + ctx.
// ---------------------------------------------------------------------------
__global__ __launch_bounds__(256) void addattn_combine(
    float* __restrict__ out, const float* __restrict__ ws) {
  const int b = blockIdx.x;
  const int t = threadIdx.x;
  const float* wl = ws;
  const float* wc = ws + 512;
  const float inv = 1.0f / (wl[2 * b] + wl[2 * b + 1]);

  float4* al4 = (float4*)(out + NB * ND + (size_t)b * NS);
#pragma unroll
  for (int j = 0; j < 2; ++j) {
    float4 v = al4[t + j * 256];
    v.x *= inv; v.y *= inv; v.z *= inv; v.w *= inv;
    al4[t + j * 256] = v;
  }
  if (t < ND)
    out[(size_t)b * ND + t] =
        (wc[(size_t)(2 * b) * ND + t] + wc[(size_t)(2 * b + 1) * ND + t]) * inv;
}

extern "C" void kernel_launch(void* const* d_in, const int* in_sizes, int n_in,
                              void* d_out, int out_size, void* d_ws,
                              size_t ws_size, hipStream_t stream) {
  const float* x = (const float*)d_in[0];
  const float* W1 = (const float*)d_in[1];
  const float* W2 = (const float*)d_in[2];
  const float* bias = (const float*)d_in[3];
  float* out = (float*)d_out;
  float* ws = (float*)d_ws;
  addattn_stream<<<NB * 2, NT, 0, stream>>>(x, W1, W2, bias, out, ws);
  addattn_combine<<<NB, 256, 0, stream>>>(out, ws);
}

// Round 8
// 49.061 us; speedup vs baseline: 6.4028x; 1.1330x over previous
//
#include <hip/hip_runtime.h>
#include <math.h>

#define NB 256
#define NS 2048
#define ND 128
#define NU 64
#define NT 512
#define TS 128
#define NTILE (NS / TS)

typedef _Float16 f16x8 __attribute__((ext_vector_type(8)));
typedef float f32x4 __attribute__((ext_vector_type(4)));

#define GLDS16(gp, lp)                                                        \
  __builtin_amdgcn_global_load_lds(                                           \
      (const __attribute__((address_space(1))) void*)(gp),                    \
      (__attribute__((address_space(3))) void*)(lp), 16, 0, 0)

__device__ __forceinline__ float tanh_fast(float v) {
  // tanh(v) = 1 - 2/(exp(2v)+1); exact saturation for large |v|.
  const float e = __expf(2.0f * v);
  return 1.0f - 2.0f * __builtin_amdgcn_rcpf(e + 1.0f);
}

__global__ __launch_bounds__(NT, 2) void addattn_mfma(
    const float* __restrict__ x,     // [NB][NS][ND]
    const float* __restrict__ W1,    // [ND][NU]
    const float* __restrict__ W2,    // [NU]
    const float* __restrict__ bias,  // [NU]
    float* __restrict__ out)         // ctx [NB][ND] ++ alpha [NB][NS]
{
  // Per-wave private x slices: wave wv owns tile rows [wv*16, wv*16+16).
  // It stages them itself (8x global_load_lds) and waits only on its OWN
  // vmcnt -> no s_barrier anywhere in the main loop. Swizzle: slice float4
  // slot (s_local, c) holds source column c ^ (s_local & 7) (both-sides XOR:
  // pre-swizzled global source + swizzled LDS read; linear GLDS dest).
  __shared__ __align__(16) float xbuf[2][TS * ND];  // 2 x 64 KiB (8 slices)
  __shared__ float ps[NS];                          // exp(score_s)
  __shared__ __align__(16) float part[16][ND];      // ctx partials
  __shared__ float red[8];

  const int b = blockIdx.x;
  const int t = threadIdx.x;
  const int lane = t & 63;
  const int wv = t >> 6;      // wave 0..7
  const int l15 = lane & 15;
  const int hi = lane >> 4;   // 0..3
  const float* xb = x + (size_t)b * NS * ND;

  // ---- per-wave tile staging: 8 x (64 lanes x 16B) = wave's 16 rows (8 KiB)
  auto stage = [&](int bi, int ti) {
    const float* src = xb + (size_t)ti * TS * ND + wv * 16 * ND;
    float* dst = &xbuf[bi][wv * 16 * ND];
#pragma unroll
    for (int j = 0; j < 8; ++j) {
      const int L = j * 64 + lane;        // 16B slot in the 512-slot slice
      const int s = L >> 5;               // slice row 0..15
      const int d4 = (L & 31) ^ (s & 7);  // source float4 column
      GLDS16(src + s * ND + d4 * 4, dst + L * 4);
    }
  };

  stage(0, 0);  // HBM starts immediately; W1 latency hides under it

  // ---- A fragments: W1^T [64u x 128k], kept in registers for the kernel.
  //      afrag[mt][kt]: A[m = mt*16 + (lane&15)][k = kt*32 + (lane>>4)*8 + j]
  f16x8 afrag[4][4];
#pragma unroll
  for (int mt = 0; mt < 4; ++mt) {
#pragma unroll
    for (int kt = 0; kt < 4; ++kt) {
      const int u = mt * 16 + l15;
      const int k0 = kt * 32 + hi * 8;
      f16x8 a;
#pragma unroll
      for (int j = 0; j < 8; ++j) a[j] = (_Float16)W1[(k0 + j) * NU + u];
      afrag[mt][kt] = a;
    }
  }
  // bias/W2 for this lane's C-fragment rows: u = mt*16 + (lane>>4)*4 + r
  float breg[4][4], wreg[4][4];
#pragma unroll
  for (int mt = 0; mt < 4; ++mt) {
#pragma unroll
    for (int r = 0; r < 4; ++r) {
      const int u = mt * 16 + hi * 4 + r;
      breg[mt][r] = bias[u];
      wreg[mt][r] = W2[u];
    }
  }

  stage(1, 1);  // second buffer in flight

  f32x4 ctxa = {0.f, 0.f, 0.f, 0.f};     // running exp(s)*x partial
  const int dq = lane & 31;              // ctx float4 column
  const int rloc = (lane >> 5) << 3;     // ctx local row base (0 or 8)

  for (int ti = 0; ti < NTILE; ++ti) {
    const int cur = ti & 1;
    // Per-wave counted wait: my 8 tile-ti loads are my oldest outstanding;
    // leave tile ti+1's 8 in flight. No cross-wave barrier.
    if (ti < NTILE - 1) {
      asm volatile("s_waitcnt vmcnt(8)" ::: "memory");
    } else {
      asm volatile("s_waitcnt vmcnt(0)" ::: "memory");
    }
    __builtin_amdgcn_sched_barrier(0);
    const float* xs = &xbuf[cur][wv * 16 * ND];  // this wave's slice

    // ---- scores: P^T = W1^T (A) x^T (B); this wave's 16 rows as B columns
    f32x4 acc[4];
#pragma unroll
    for (int mt = 0; mt < 4; ++mt) acc[mt] = (f32x4){0.f, 0.f, 0.f, 0.f};
    const int rb = l15 * 32;
    const int sw = l15 & 7;
#pragma unroll
    for (int kt = 0; kt < 4; ++kt) {
      const int d4a = kt * 8 + hi * 2;
      const float4 v0 = *(const float4*)(xs + (rb + ((d4a + 0) ^ sw)) * 4);
      const float4 v1 = *(const float4*)(xs + (rb + ((d4a + 1) ^ sw)) * 4);
      f16x8 bf;
      bf[0] = (_Float16)v0.x; bf[1] = (_Float16)v0.y;
      bf[2] = (_Float16)v0.z; bf[3] = (_Float16)v0.w;
      bf[4] = (_Float16)v1.x; bf[5] = (_Float16)v1.y;
      bf[6] = (_Float16)v1.z; bf[7] = (_Float16)v1.w;
#pragma unroll
      for (int mt = 0; mt < 4; ++mt)
        acc[mt] = __builtin_amdgcn_mfma_f32_16x16x32_f16(afrag[mt][kt], bf,
                                                         acc[mt], 0, 0, 0);
    }
    // ---- epilogue: score2_s = sum_u tanh(P + b)*W2; reduce over lane-hi
    float s2 = 0.f;
#pragma unroll
    for (int mt = 0; mt < 4; ++mt) {
#pragma unroll
      for (int r = 0; r < 4; ++r)
        s2 = fmaf(tanh_fast(acc[mt][r] + breg[mt][r]), wreg[mt][r], s2);
    }
    s2 += __shfl_xor(s2, 16);
    s2 += __shfl_xor(s2, 32);
    // |score2| <= sum|W2| ~ 6.4 -> exp() safe in fp32, no max subtraction.
    const float p = __expf(s2);  // valid in all lanes for row = lane&15
    if (lane < 16) ps[ti * TS + wv * 16 + l15] = p;  // read after final sync

    // ---- ctx accumulation over this wave's 16 rows (p via shfl)
#pragma unroll
    for (int r8 = 0; r8 < 8; ++r8) {
      const int sr = rloc + r8;  // local row 0..15
      const float pv = __shfl(p, sr);
      const float4 xv = *(const float4*)(xs + (sr * 32 + (dq ^ (sr & 7))) * 4);
      ctxa[0] = fmaf(pv, xv.x, ctxa[0]);
      ctxa[1] = fmaf(pv, xv.y, ctxa[1]);
      ctxa[2] = fmaf(pv, xv.z, ctxa[2]);
      ctxa[3] = fmaf(pv, xv.w, ctxa[3]);
    }

    // Re-stage this wave's slice for tile ti+2 (only this wave reads it).
    if (ti + 2 < NTILE) stage(cur, ti + 2);
  }
  __syncthreads();  // orders ps / part for the cross-wave finale

  // ---- finale: l = sum exp(s); alpha = exp(s)/l; ctx = partials/l
  float lsum = 0.f;
#pragma unroll
  for (int j = 0; j < 4; ++j) lsum += ps[t + NT * j];
#pragma unroll
  for (int off = 32; off > 0; off >>= 1) lsum += __shfl_xor(lsum, off);
  if (lane == 0) red[wv] = lsum;
  *(float4*)(&part[t >> 5][dq * 4]) =
      make_float4(ctxa[0], ctxa[1], ctxa[2], ctxa[3]);
  __syncthreads();
  float l = 0.f;
#pragma unroll
  for (int j = 0; j < 8; ++j) l += red[j];
  const float inv = 1.0f / l;

  float* alpha_out = out + NB * ND;
#pragma unroll
  for (int j = 0; j < 4; ++j) {
    const int s = t + NT * j;
    alpha_out[(size_t)b * NS + s] = ps[s] * inv;
  }
  if (t < ND) {
    float sum = 0.f;
#pragma unroll
    for (int g = 0; g < 16; ++g) sum += part[g][t];
    out[(size_t)b * ND + t] = sum * inv;
  }
}

extern "C" void kernel_launch(void* const* d_in, const int* in_sizes, int n_in,
                              void* d_out, int out_size, void* d_ws,
                              size_t ws_size, hipStream_t stream) {
  const float* x = (const float*)d_in[0];
  const float* W1 = (const float*)d_in[1];
  const float* W2 = (const float*)d_in[2];
  const float* bias = (const float*)d_in[3];
  float* out = (float*)d_out;
  addattn_mfma<<<NB, NT, 0, stream>>>(x, W1, W2, bias, out);
}